// Round 2
// baseline (16054.590 us; speedup 1.0000x reference)
//
#include <hip/hip_runtime.h>
#include <hip/hip_bf16.h>
#include <math.h>

// ---------------------------------------------------------------------------
// 3-layer GCN (PyG GCNConv, no self loops).
// R2: de-spill the f32 GEMM. R1 showed VGPR=256 + 2.5GB scratch writes per
// GEMM dispatch (spill-bound, VALUBusy 11%). Fix: global_load_lds staging
// (no staging VGPRs / ds_writes) + __launch_bounds__(256,4) cap. Tile shape
// unchanged (BM=64,BN=256,BK=32) — its LDS read patterns are conflict-free:
//   Ws[kk*256+tc*4]  : 64 lanes x contiguous float4 = 1KB, 2-way (free)
//   Xs[(wave*16+rr)*32+kk] : wave-uniform broadcast (free)
// ---------------------------------------------------------------------------

#define THREADS 256

__global__ void k_deg(const int* __restrict__ dst, int* __restrict__ deg, int E) {
    int e = blockIdx.x * THREADS + threadIdx.x;
    if (e < E) atomicAdd(&deg[dst[e]], 1);
}

__global__ void k_dinv(const int* __restrict__ deg, float* __restrict__ dinv, int N) {
    int i = blockIdx.x * THREADS + threadIdx.x;
    if (i < N) {
        int d = deg[i];
        dinv[i] = (d > 0) ? rsqrtf((float)d) : 0.0f;
    }
}

// exclusive scan of deg -> rowp, 3-pass
__global__ void k_scan1(const int* __restrict__ deg, int* __restrict__ rowp,
                        int* __restrict__ bsums, int N) {
    __shared__ int s[THREADS];
    int idx = blockIdx.x * THREADS + threadIdx.x;
    int v = (idx < N) ? deg[idx] : 0;
    s[threadIdx.x] = v;
    __syncthreads();
    for (int off = 1; off < THREADS; off <<= 1) {
        int t = (threadIdx.x >= off) ? s[threadIdx.x - off] : 0;
        __syncthreads();
        s[threadIdx.x] += t;
        __syncthreads();
    }
    if (idx < N) rowp[idx] = s[threadIdx.x] - v;   // exclusive
    if (threadIdx.x == THREADS - 1) bsums[blockIdx.x] = s[threadIdx.x];
}

__global__ void k_scan2(int* __restrict__ bsums, int NB) {
    __shared__ int s[512];
    int v = (threadIdx.x < (unsigned)NB) ? bsums[threadIdx.x] : 0;
    s[threadIdx.x] = v;
    __syncthreads();
    for (int off = 1; off < 512; off <<= 1) {
        int t = (threadIdx.x >= (unsigned)off) ? s[threadIdx.x - off] : 0;
        __syncthreads();
        s[threadIdx.x] += t;
        __syncthreads();
    }
    if (threadIdx.x < (unsigned)NB) bsums[threadIdx.x] = s[threadIdx.x] - v;  // exclusive
}

__global__ void k_scan3(int* __restrict__ rowp, const int* __restrict__ bsums, int N) {
    int idx = blockIdx.x * THREADS + threadIdx.x;
    if (idx < N) rowp[idx] += bsums[blockIdx.x];
}

__global__ void k_fill(const int* __restrict__ src, const int* __restrict__ dst,
                       const float* __restrict__ dinv, const int* __restrict__ rowp,
                       int* __restrict__ cnt, int* __restrict__ esrc,
                       float* __restrict__ enorm, int E) {
    int e = blockIdx.x * THREADS + threadIdx.x;
    if (e >= E) return;
    int s = src[e], d = dst[e];
    int pos = rowp[d] + atomicAdd(&cnt[d], 1);
    esrc[pos]  = s;
    enorm[pos] = dinv[s] * dinv[d];
}

__device__ __forceinline__ void load_lds16(const float* g, float* l) {
    __builtin_amdgcn_global_load_lds(
        (const __attribute__((address_space(1))) void*)g,
        (__attribute__((address_space(3))) void*)l, 16, 0, 0);
}

// C[N,256] = X[N,K] @ W[K,256], f32 vector ALU, BM=64 BN=256 BK=32.
// 256 threads = 4 waves. tc = tid&63 (4 cols), wave = row group of 16 rows.
template <int K>
__global__ __launch_bounds__(256, 4) void k_gemm(const float* __restrict__ X,
                                                 const float* __restrict__ W,
                                                 float* __restrict__ C, int N) {
    __shared__ float Xs[64 * 32];    // [r][k]  8 KB
    __shared__ float Ws[32 * 256];   // [k][c] 32 KB
    const int tid  = threadIdx.x;
    const int lane = tid & 63;
    const int wv   = tid >> 6;       // wave id 0..3 == row group
    const int tc   = lane;           // col4 index
    const int row0 = blockIdx.x * 64;

    float acc[16][4];
#pragma unroll
    for (int r = 0; r < 16; ++r)
#pragma unroll
        for (int j = 0; j < 4; ++j) acc[r][j] = 0.0f;

    for (int k0 = 0; k0 < K; k0 += 32) {
        // W tile: rows k0..k0+31 of W are contiguous; wave wv stages rows
        // wv*8+i (1KB each: 64 lanes x 16B).
#pragma unroll
        for (int i = 0; i < 8; ++i) {
            int r = wv * 8 + i;
            load_lds16(&W[(size_t)(k0 + r) * 256 + lane * 4], &Ws[r * 256]);
        }
        // X tile: 8 chunks of 8 rows x 32 floats (1KB); wave wv stages
        // chunks wv*2, wv*2+1. Lane l -> row c*8 + l/8, floats (l&7)*4.
#pragma unroll
        for (int i = 0; i < 2; ++i) {
            int c = wv * 2 + i;
            int gr = row0 + c * 8 + (lane >> 3);
            if (gr >= N) gr = N - 1;              // clamp (values unused)
            load_lds16(&X[(size_t)gr * K + k0 + (lane & 7) * 4], &Xs[c * 256]);
        }
        __syncthreads();

#pragma unroll
        for (int kk = 0; kk < 32; kk += 4) {
            float4 w0 = *(const float4*)&Ws[(kk + 0) * 256 + tc * 4];
            float4 w1 = *(const float4*)&Ws[(kk + 1) * 256 + tc * 4];
            float4 w2 = *(const float4*)&Ws[(kk + 2) * 256 + tc * 4];
            float4 w3 = *(const float4*)&Ws[(kk + 3) * 256 + tc * 4];
#pragma unroll
            for (int rr = 0; rr < 16; ++rr) {
                float4 xv = *(const float4*)&Xs[(wv * 16 + rr) * 32 + kk];
                acc[rr][0] += xv.x * w0.x + xv.y * w1.x + xv.z * w2.x + xv.w * w3.x;
                acc[rr][1] += xv.x * w0.y + xv.y * w1.y + xv.z * w2.y + xv.w * w3.y;
                acc[rr][2] += xv.x * w0.z + xv.y * w1.z + xv.z * w2.z + xv.w * w3.z;
                acc[rr][3] += xv.x * w0.w + xv.y * w1.w + xv.z * w2.w + xv.w * w3.w;
            }
        }
        __syncthreads();
    }

#pragma unroll
    for (int rr = 0; rr < 16; ++rr) {
        int gr = row0 + wv * 16 + rr;
        if (gr < N) {
            *(float4*)&C[(size_t)gr * 256 + tc * 4] =
                make_float4(acc[rr][0], acc[rr][1], acc[rr][2], acc[rr][3]);
        }
    }
}

__device__ __forceinline__ float elu1(float x) {
    return x > 0.0f ? x : expm1f(x);
}

// one wave per node; lane handles 4 channels (float4).
__global__ __launch_bounds__(256) void k_agg(const float* __restrict__ h,
                                             const int* __restrict__ rowp,
                                             const int* __restrict__ deg,
                                             const int* __restrict__ esrc,
                                             const float* __restrict__ enorm,
                                             const float* __restrict__ bias,
                                             float* __restrict__ out, int N) {
    int wave = threadIdx.x >> 6;
    int lane = threadIdx.x & 63;
    int node = blockIdx.x * 4 + wave;
    if (node >= N) return;

    int start = rowp[node];
    int cnt   = deg[node];

    float4 acc = make_float4(0.f, 0.f, 0.f, 0.f);
    for (int e = 0; e < cnt; ++e) {
        int   s   = esrc[start + e];
        float nrm = enorm[start + e];
        float4 hv = *(const float4*)&h[(size_t)s * 256 + lane * 4];
        acc.x += nrm * hv.x;
        acc.y += nrm * hv.y;
        acc.z += nrm * hv.z;
        acc.w += nrm * hv.w;
    }
    float4 b4 = *(const float4*)&bias[lane * 4];
    float4 o;
    o.x = elu1(acc.x + b4.x);
    o.y = elu1(acc.y + b4.y);
    o.z = elu1(acc.z + b4.z);
    o.w = elu1(acc.w + b4.w);
    *(float4*)&out[(size_t)node * 256 + lane * 4] = o;
}

static inline size_t alignup(size_t x) { return (x + 255) & ~(size_t)255; }

extern "C" void kernel_launch(void* const* d_in, const int* in_sizes, int n_in,
                              void* d_out, int out_size, void* d_ws, size_t ws_size,
                              hipStream_t stream) {
    const float* x  = (const float*)d_in[0];
    const int*   ei = (const int*)d_in[1];
    const float* W1 = (const float*)d_in[2];
    const float* b1 = (const float*)d_in[3];
    const float* W2 = (const float*)d_in[4];
    const float* b2 = (const float*)d_in[5];
    const float* W3 = (const float*)d_in[6];
    const float* b3 = (const float*)d_in[7];
    float* out = (float*)d_out;

    const int N = in_sizes[0] / 64;   // 100000
    const int E = in_sizes[1] / 2;    // 600000
    const int* src = ei;
    const int* dst = ei + E;

    // workspace carve
    char* p = (char*)d_ws;
    int*   deg   = (int*)p;   p += alignup((size_t)N * 4);
    float* dinv  = (float*)p; p += alignup((size_t)N * 4);
    int*   rowp  = (int*)p;   p += alignup((size_t)N * 4);
    int*   cnt   = (int*)p;   p += alignup((size_t)N * 4);
    int*   esrc  = (int*)p;   p += alignup((size_t)E * 4);
    float* enorm = (float*)p; p += alignup((size_t)E * 4);
    const int NB = (N + THREADS - 1) / THREADS;
    int*   bsums = (int*)p;   p += alignup((size_t)NB * 4);
    float* bufA  = (float*)p; p += alignup((size_t)N * 256 * 4);

    const int EB = (E + THREADS - 1) / THREADS;
    const int GB = (N + 63) / 64;       // gemm blocks
    const int AB = (N + 3) / 4;         // agg blocks (4 waves/block)

    hipMemsetAsync(deg, 0, (size_t)N * 4, stream);
    hipMemsetAsync(cnt, 0, (size_t)N * 4, stream);

    k_deg<<<EB, THREADS, 0, stream>>>(dst, deg, E);
    k_dinv<<<NB, THREADS, 0, stream>>>(deg, dinv, N);
    k_scan1<<<NB, THREADS, 0, stream>>>(deg, rowp, bsums, N);
    k_scan2<<<1, 512, 0, stream>>>(bsums, NB);
    k_scan3<<<NB, THREADS, 0, stream>>>(rowp, bsums, N);
    k_fill<<<EB, THREADS, 0, stream>>>(src, dst, dinv, rowp, cnt, esrc, enorm, E);

    // layer 1: x[N,64] @ W1 -> bufA ; agg -> d_out
    k_gemm<64><<<GB, THREADS, 0, stream>>>(x, W1, bufA, N);
    k_agg<<<AB, THREADS, 0, stream>>>(bufA, rowp, deg, esrc, enorm, b1, out, N);
    // layer 2: d_out @ W2 -> bufA ; agg -> d_out
    k_gemm<256><<<GB, THREADS, 0, stream>>>(out, W2, bufA, N);
    k_agg<<<AB, THREADS, 0, stream>>>(bufA, rowp, deg, esrc, enorm, b2, out, N);
    // layer 3
    k_gemm<256><<<GB, THREADS, 0, stream>>>(out, W3, bufA, N);
    k_agg<<<AB, THREADS, 0, stream>>>(bufA, rowp, deg, esrc, enorm, b3, out, N);
}

// Round 3
// 5597.480 us; speedup vs baseline: 2.8682x; 2.8682x over previous
//
#include <hip/hip_runtime.h>
#include <hip/hip_bf16.h>
#include <math.h>

// ---------------------------------------------------------------------------
// 3-layer GCN (PyG GCNConv, no self loops).
// R3: kill the GEMM register spill. R1 (VGPR=256) and R2 (VGPR=64 via bad
// launch_bounds) both spilled the accumulator tile -> GBs of scratch traffic.
// Fix: 512-thread blocks, per-thread tile shrunk to acc[8][4] (32 VGPRs),
// live set ~70 regs, no launch_bounds cap, #pragma unroll 1 on the K loop
// to prevent unroll-and-jam. Tile BM=64 BN=256 BK=32 unchanged; LDS reads
// stay conflict-free (Ws: contiguous 1KB/wave; Xs: wave-uniform broadcast).
// ---------------------------------------------------------------------------

#define THREADS 256

__global__ void k_deg(const int* __restrict__ dst, int* __restrict__ deg, int E) {
    int e = blockIdx.x * THREADS + threadIdx.x;
    if (e < E) atomicAdd(&deg[dst[e]], 1);
}

__global__ void k_dinv(const int* __restrict__ deg, float* __restrict__ dinv, int N) {
    int i = blockIdx.x * THREADS + threadIdx.x;
    if (i < N) {
        int d = deg[i];
        dinv[i] = (d > 0) ? rsqrtf((float)d) : 0.0f;
    }
}

// exclusive scan of deg -> rowp, 3-pass
__global__ void k_scan1(const int* __restrict__ deg, int* __restrict__ rowp,
                        int* __restrict__ bsums, int N) {
    __shared__ int s[THREADS];
    int idx = blockIdx.x * THREADS + threadIdx.x;
    int v = (idx < N) ? deg[idx] : 0;
    s[threadIdx.x] = v;
    __syncthreads();
    for (int off = 1; off < THREADS; off <<= 1) {
        int t = (threadIdx.x >= off) ? s[threadIdx.x - off] : 0;
        __syncthreads();
        s[threadIdx.x] += t;
        __syncthreads();
    }
    if (idx < N) rowp[idx] = s[threadIdx.x] - v;   // exclusive
    if (threadIdx.x == THREADS - 1) bsums[blockIdx.x] = s[threadIdx.x];
}

__global__ void k_scan2(int* __restrict__ bsums, int NB) {
    __shared__ int s[512];
    int v = (threadIdx.x < (unsigned)NB) ? bsums[threadIdx.x] : 0;
    s[threadIdx.x] = v;
    __syncthreads();
    for (int off = 1; off < 512; off <<= 1) {
        int t = (threadIdx.x >= (unsigned)off) ? s[threadIdx.x - off] : 0;
        __syncthreads();
        s[threadIdx.x] += t;
        __syncthreads();
    }
    if (threadIdx.x < (unsigned)NB) bsums[threadIdx.x] = s[threadIdx.x] - v;  // exclusive
}

__global__ void k_scan3(int* __restrict__ rowp, const int* __restrict__ bsums, int N) {
    int idx = blockIdx.x * THREADS + threadIdx.x;
    if (idx < N) rowp[idx] += bsums[blockIdx.x];
}

__global__ void k_fill(const int* __restrict__ src, const int* __restrict__ dst,
                       const float* __restrict__ dinv, const int* __restrict__ rowp,
                       int* __restrict__ cnt, int* __restrict__ esrc,
                       float* __restrict__ enorm, int E) {
    int e = blockIdx.x * THREADS + threadIdx.x;
    if (e >= E) return;
    int s = src[e], d = dst[e];
    int pos = rowp[d] + atomicAdd(&cnt[d], 1);
    esrc[pos]  = s;
    enorm[pos] = dinv[s] * dinv[d];
}

__device__ __forceinline__ void load_lds16(const float* g, float* l) {
    __builtin_amdgcn_global_load_lds(
        (const __attribute__((address_space(1))) void*)g,
        (__attribute__((address_space(3))) void*)l, 16, 0, 0);
}

// C[N,256] = X[N,K] @ W[K,256], f32 vector ALU, BM=64 BN=256 BK=32.
// 512 threads = 8 waves. Wave wv owns rows wv*8..wv*8+7; lane owns 4 cols.
template <int K>
__global__ void k_gemm(const float* __restrict__ X,
                       const float* __restrict__ W,
                       float* __restrict__ C, int N) {
    __shared__ float Xs[64 * 32];    // [r][k]  8 KB
    __shared__ float Ws[32 * 256];   // [k][c] 32 KB
    const int tid  = threadIdx.x;
    const int lane = tid & 63;
    const int wv   = tid >> 6;       // wave id 0..7
    const int row0 = blockIdx.x * 64;

    float acc[8][4];
#pragma unroll
    for (int r = 0; r < 8; ++r)
#pragma unroll
        for (int j = 0; j < 4; ++j) acc[r][j] = 0.0f;

#pragma unroll 1
    for (int k0 = 0; k0 < K; k0 += 32) {
        // W tile: 32 rows x 1KB. Wave wv stages rows wv*4+i (i<4):
        // 64 lanes x 16B contiguous per row.
#pragma unroll
        for (int i = 0; i < 4; ++i) {
            int r = wv * 4 + i;
            load_lds16(&W[(size_t)(k0 + r) * 256 + lane * 4], &Ws[r * 256]);
        }
        // X tile: 8 chunks of 8 rows x 32 floats (1KB each); wave wv stages
        // chunk wv. Lane l -> row wv*8 + l/8, floats (l&7)*4. LDS linear in l.
        {
            int gr = row0 + wv * 8 + (lane >> 3);
            if (gr >= N) gr = N - 1;              // clamp (values unused)
            load_lds16(&X[(size_t)gr * K + k0 + (lane & 7) * 4], &Xs[wv * 256]);
        }
        __syncthreads();

#pragma unroll
        for (int kk = 0; kk < 32; kk += 4) {
            float4 w0 = *(const float4*)&Ws[(kk + 0) * 256 + lane * 4];
            float4 w1 = *(const float4*)&Ws[(kk + 1) * 256 + lane * 4];
            float4 w2 = *(const float4*)&Ws[(kk + 2) * 256 + lane * 4];
            float4 w3 = *(const float4*)&Ws[(kk + 3) * 256 + lane * 4];
#pragma unroll
            for (int r = 0; r < 8; ++r) {
                float4 xv = *(const float4*)&Xs[(wv * 8 + r) * 32 + kk];
                acc[r][0] += xv.x * w0.x + xv.y * w1.x + xv.z * w2.x + xv.w * w3.x;
                acc[r][1] += xv.x * w0.y + xv.y * w1.y + xv.z * w2.y + xv.w * w3.y;
                acc[r][2] += xv.x * w0.z + xv.y * w1.z + xv.z * w2.z + xv.w * w3.z;
                acc[r][3] += xv.x * w0.w + xv.y * w1.w + xv.z * w2.w + xv.w * w3.w;
            }
        }
        __syncthreads();
    }

#pragma unroll
    for (int r = 0; r < 8; ++r) {
        int gr = row0 + wv * 8 + r;
        if (gr < N) {
            *(float4*)&C[(size_t)gr * 256 + lane * 4] =
                make_float4(acc[r][0], acc[r][1], acc[r][2], acc[r][3]);
        }
    }
}

__device__ __forceinline__ float elu1(float x) {
    return x > 0.0f ? x : expm1f(x);
}

// one wave per node; lane handles 4 channels (float4).
__global__ __launch_bounds__(256) void k_agg(const float* __restrict__ h,
                                             const int* __restrict__ rowp,
                                             const int* __restrict__ deg,
                                             const int* __restrict__ esrc,
                                             const float* __restrict__ enorm,
                                             const float* __restrict__ bias,
                                             float* __restrict__ out, int N) {
    int wave = threadIdx.x >> 6;
    int lane = threadIdx.x & 63;
    int node = blockIdx.x * 4 + wave;
    if (node >= N) return;

    int start = rowp[node];
    int cnt   = deg[node];

    float4 acc = make_float4(0.f, 0.f, 0.f, 0.f);
    for (int e = 0; e < cnt; ++e) {
        int   s   = esrc[start + e];
        float nrm = enorm[start + e];
        float4 hv = *(const float4*)&h[(size_t)s * 256 + lane * 4];
        acc.x += nrm * hv.x;
        acc.y += nrm * hv.y;
        acc.z += nrm * hv.z;
        acc.w += nrm * hv.w;
    }
    float4 b4 = *(const float4*)&bias[lane * 4];
    float4 o;
    o.x = elu1(acc.x + b4.x);
    o.y = elu1(acc.y + b4.y);
    o.z = elu1(acc.z + b4.z);
    o.w = elu1(acc.w + b4.w);
    *(float4*)&out[(size_t)node * 256 + lane * 4] = o;
}

static inline size_t alignup(size_t x) { return (x + 255) & ~(size_t)255; }

extern "C" void kernel_launch(void* const* d_in, const int* in_sizes, int n_in,
                              void* d_out, int out_size, void* d_ws, size_t ws_size,
                              hipStream_t stream) {
    const float* x  = (const float*)d_in[0];
    const int*   ei = (const int*)d_in[1];
    const float* W1 = (const float*)d_in[2];
    const float* b1 = (const float*)d_in[3];
    const float* W2 = (const float*)d_in[4];
    const float* b2 = (const float*)d_in[5];
    const float* W3 = (const float*)d_in[6];
    const float* b3 = (const float*)d_in[7];
    float* out = (float*)d_out;

    const int N = in_sizes[0] / 64;   // 100000
    const int E = in_sizes[1] / 2;    // 600000
    const int* src = ei;
    const int* dst = ei + E;

    // workspace carve
    char* p = (char*)d_ws;
    int*   deg   = (int*)p;   p += alignup((size_t)N * 4);
    float* dinv  = (float*)p; p += alignup((size_t)N * 4);
    int*   rowp  = (int*)p;   p += alignup((size_t)N * 4);
    int*   cnt   = (int*)p;   p += alignup((size_t)N * 4);
    int*   esrc  = (int*)p;   p += alignup((size_t)E * 4);
    float* enorm = (float*)p; p += alignup((size_t)E * 4);
    const int NB = (N + THREADS - 1) / THREADS;
    int*   bsums = (int*)p;   p += alignup((size_t)NB * 4);
    float* bufA  = (float*)p; p += alignup((size_t)N * 256 * 4);

    const int EB = (E + THREADS - 1) / THREADS;
    const int GB = (N + 63) / 64;       // gemm blocks
    const int AB = (N + 3) / 4;         // agg blocks (4 waves/block)

    hipMemsetAsync(deg, 0, (size_t)N * 4, stream);
    hipMemsetAsync(cnt, 0, (size_t)N * 4, stream);

    k_deg<<<EB, THREADS, 0, stream>>>(dst, deg, E);
    k_dinv<<<NB, THREADS, 0, stream>>>(deg, dinv, N);
    k_scan1<<<NB, THREADS, 0, stream>>>(deg, rowp, bsums, N);
    k_scan2<<<1, 512, 0, stream>>>(bsums, NB);
    k_scan3<<<NB, THREADS, 0, stream>>>(rowp, bsums, N);
    k_fill<<<EB, THREADS, 0, stream>>>(src, dst, dinv, rowp, cnt, esrc, enorm, E);

    // layer 1: x[N,64] @ W1 -> bufA ; agg -> d_out
    k_gemm<64><<<GB, 512, 0, stream>>>(x, W1, bufA, N);
    k_agg<<<AB, THREADS, 0, stream>>>(bufA, rowp, deg, esrc, enorm, b1, out, N);
    // layer 2: d_out @ W2 -> bufA ; agg -> d_out
    k_gemm<256><<<GB, 512, 0, stream>>>(out, W2, bufA, N);
    k_agg<<<AB, THREADS, 0, stream>>>(bufA, rowp, deg, esrc, enorm, b2, out, N);
    // layer 3
    k_gemm<256><<<GB, 512, 0, stream>>>(out, W3, bufA, N);
    k_agg<<<AB, THREADS, 0, stream>>>(bufA, rowp, deg, esrc, enorm, b3, out, N);
}

// Round 4
// 1010.246 us; speedup vs baseline: 15.8918x; 5.5407x over previous
//
#include <hip/hip_runtime.h>
#include <hip/hip_bf16.h>
#include <math.h>

// ---------------------------------------------------------------------------
// 3-layer GCN (PyG GCNConv, no self loops).
// R4: abandon the f32 vector GEMM (3 rounds of allocator-induced scratch
// spill: R1 VGPR=256/2.5GB writes, R2/R3 VGPR=64/5-8GB). New GEMM path:
// split-bf16 MFMA (x = hi + lo, 3x mfma_f32_16x16x32_bf16 per k-step;
// dropped lo*lo term ~2^-18 rel, ~1e-4 abs added error vs passing 2e-3).
// No LDS, no barriers: A split f32->bf16x2 on the fly in-register; B from
// pre-split+transposed W planes (256 KB, L2-resident). acc[16] f32x4 = 64
// VGPRs, all statically indexed.
// MFMA layouts (guide m89-verified): A row=lane%16 k=8*(lane>>4)+e;
// B col=lane%16 same k-map (k-map errors cancel A-vs-B); C/D row=
// 4*(lane>>4)+reg, col=lane&15.
// ---------------------------------------------------------------------------

#define THREADS 256

typedef __attribute__((ext_vector_type(8))) short short8;
typedef __attribute__((ext_vector_type(4))) float f32x4;

__global__ void k_deg(const int* __restrict__ dst, int* __restrict__ deg, int E) {
    int e = blockIdx.x * THREADS + threadIdx.x;
    if (e < E) atomicAdd(&deg[dst[e]], 1);
}

__global__ void k_dinv(const int* __restrict__ deg, float* __restrict__ dinv, int N) {
    int i = blockIdx.x * THREADS + threadIdx.x;
    if (i < N) {
        int d = deg[i];
        dinv[i] = (d > 0) ? rsqrtf((float)d) : 0.0f;
    }
}

__global__ void k_scan1(const int* __restrict__ deg, int* __restrict__ rowp,
                        int* __restrict__ bsums, int N) {
    __shared__ int s[THREADS];
    int idx = blockIdx.x * THREADS + threadIdx.x;
    int v = (idx < N) ? deg[idx] : 0;
    s[threadIdx.x] = v;
    __syncthreads();
    for (int off = 1; off < THREADS; off <<= 1) {
        int t = (threadIdx.x >= off) ? s[threadIdx.x - off] : 0;
        __syncthreads();
        s[threadIdx.x] += t;
        __syncthreads();
    }
    if (idx < N) rowp[idx] = s[threadIdx.x] - v;   // exclusive
    if (threadIdx.x == THREADS - 1) bsums[blockIdx.x] = s[threadIdx.x];
}

__global__ void k_scan2(int* __restrict__ bsums, int NB) {
    __shared__ int s[512];
    int v = (threadIdx.x < (unsigned)NB) ? bsums[threadIdx.x] : 0;
    s[threadIdx.x] = v;
    __syncthreads();
    for (int off = 1; off < 512; off <<= 1) {
        int t = (threadIdx.x >= (unsigned)off) ? s[threadIdx.x - off] : 0;
        __syncthreads();
        s[threadIdx.x] += t;
        __syncthreads();
    }
    if (threadIdx.x < (unsigned)NB) bsums[threadIdx.x] = s[threadIdx.x] - v;  // exclusive
}

__global__ void k_scan3(int* __restrict__ rowp, const int* __restrict__ bsums, int N) {
    int idx = blockIdx.x * THREADS + threadIdx.x;
    if (idx < N) rowp[idx] += bsums[blockIdx.x];
}

__global__ void k_fill(const int* __restrict__ src, const int* __restrict__ dst,
                       const float* __restrict__ dinv, const int* __restrict__ rowp,
                       int* __restrict__ cnt, int* __restrict__ esrc,
                       float* __restrict__ enorm, int E) {
    int e = blockIdx.x * THREADS + threadIdx.x;
    if (e >= E) return;
    int s = src[e], d = dst[e];
    int pos = rowp[d] + atomicAdd(&cnt[d], 1);
    esrc[pos]  = s;
    enorm[pos] = dinv[s] * dinv[d];
}

// ---- bf16 split helpers (round-to-nearest-even) ----
__device__ __forceinline__ unsigned bf16rn(float x) {
    unsigned u = __float_as_uint(x);
    return (u + 0x7FFFu + ((u >> 16) & 1u)) >> 16;
}
__device__ __forceinline__ void split1(float x, short8& h, short8& l, int e) {
    unsigned hb = bf16rn(x);
    float hf = __uint_as_float(hb << 16);
    h[e] = (short)hb;
    l[e] = (short)bf16rn(x - hf);
}

// W[K,256] f32 -> Wt_hi/Wt_lo [256][K] bf16 (transposed planes)
__global__ void k_wsplit(const float* __restrict__ W, short* __restrict__ th,
                         short* __restrict__ tl, int K) {
    int idx = blockIdx.x * THREADS + threadIdx.x;
    if (idx >= 256 * K) return;
    int c = idx / K;
    int k = idx - c * K;
    float w = W[(size_t)k * 256 + c];
    unsigned hb = bf16rn(w);
    float hf = __uint_as_float(hb << 16);
    th[idx] = (short)hb;
    tl[idx] = (short)bf16rn(w - hf);
}

// C[N,256] = act[N,K] @ W[K,256] via split-bf16 MFMA.
// Block = 256 threads = 4 waves; wave wv owns rows blockIdx*64 + wv*16 .. +15,
// all 256 cols (16 col-tiles). No LDS.
template <int K>
__global__ __launch_bounds__(256) void k_mgemm(const float* __restrict__ act,
                                               const short* __restrict__ Bh,
                                               const short* __restrict__ Bl,
                                               float* __restrict__ C, int N) {
    const int lane = threadIdx.x & 63;
    const int wv   = threadIdx.x >> 6;
    const int row0 = blockIdx.x * 64 + wv * 16;
    const int r    = lane & 15;       // A row within tile / C col within tile
    const int kb   = lane >> 4;       // k sub-block 0..3

    int grow = row0 + r;
    if (grow >= N) grow = N - 1;      // clamp; junk rows never written
    const float* ap = act + (size_t)grow * K + kb * 8;

    f32x4 acc[16];
#pragma unroll
    for (int ct = 0; ct < 16; ++ct) acc[ct] = (f32x4)0.0f;

#pragma unroll 1
    for (int t = 0; t < K / 32; ++t) {
        // A fragment: 8 consecutive f32, split to hi/lo bf16 in-register
        float4 f0 = *(const float4*)(ap + t * 32);
        float4 f1 = *(const float4*)(ap + t * 32 + 4);
        short8 ah, al;
        split1(f0.x, ah, al, 0); split1(f0.y, ah, al, 1);
        split1(f0.z, ah, al, 2); split1(f0.w, ah, al, 3);
        split1(f1.x, ah, al, 4); split1(f1.y, ah, al, 5);
        split1(f1.z, ah, al, 6); split1(f1.w, ah, al, 7);

#pragma unroll
        for (int ct = 0; ct < 16; ++ct) {
            const size_t boff = (size_t)(ct * 16 + r) * K + t * 32 + kb * 8;
            short8 bh = *(const short8*)(Bh + boff);
            short8 bl = *(const short8*)(Bl + boff);
            acc[ct] = __builtin_amdgcn_mfma_f32_16x16x32_bf16(ah, bh, acc[ct], 0, 0, 0);
            acc[ct] = __builtin_amdgcn_mfma_f32_16x16x32_bf16(ah, bl, acc[ct], 0, 0, 0);
            acc[ct] = __builtin_amdgcn_mfma_f32_16x16x32_bf16(al, bh, acc[ct], 0, 0, 0);
        }
    }

    // C/D: row = row0 + kb*4 + jr, col = ct*16 + r
    const int crow0 = row0 + kb * 4;
#pragma unroll
    for (int jr = 0; jr < 4; ++jr) {
        int gr = crow0 + jr;
        if (gr < N) {
            float* cp = C + (size_t)gr * 256 + r;
#pragma unroll
            for (int ct = 0; ct < 16; ++ct) cp[ct * 16] = acc[ct][jr];
        }
    }
}

__device__ __forceinline__ float elu1(float x) {
    return x > 0.0f ? x : expm1f(x);
}

// one wave per node; lane handles 4 channels (float4).
__global__ __launch_bounds__(256) void k_agg(const float* __restrict__ h,
                                             const int* __restrict__ rowp,
                                             const int* __restrict__ deg,
                                             const int* __restrict__ esrc,
                                             const float* __restrict__ enorm,
                                             const float* __restrict__ bias,
                                             float* __restrict__ out, int N) {
    int wave = threadIdx.x >> 6;
    int lane = threadIdx.x & 63;
    int node = blockIdx.x * 4 + wave;
    if (node >= N) return;

    int start = rowp[node];
    int cnt   = deg[node];

    float4 acc = make_float4(0.f, 0.f, 0.f, 0.f);
    for (int e = 0; e < cnt; ++e) {
        int   s   = esrc[start + e];
        float nrm = enorm[start + e];
        float4 hv = *(const float4*)&h[(size_t)s * 256 + lane * 4];
        acc.x += nrm * hv.x;
        acc.y += nrm * hv.y;
        acc.z += nrm * hv.z;
        acc.w += nrm * hv.w;
    }
    float4 b4 = *(const float4*)&bias[lane * 4];
    float4 o;
    o.x = elu1(acc.x + b4.x);
    o.y = elu1(acc.y + b4.y);
    o.z = elu1(acc.z + b4.z);
    o.w = elu1(acc.w + b4.w);
    *(float4*)&out[(size_t)node * 256 + lane * 4] = o;
}

static inline size_t alignup(size_t x) { return (x + 255) & ~(size_t)255; }

extern "C" void kernel_launch(void* const* d_in, const int* in_sizes, int n_in,
                              void* d_out, int out_size, void* d_ws, size_t ws_size,
                              hipStream_t stream) {
    const float* x  = (const float*)d_in[0];
    const int*   ei = (const int*)d_in[1];
    const float* W1 = (const float*)d_in[2];
    const float* b1 = (const float*)d_in[3];
    const float* W2 = (const float*)d_in[4];
    const float* b2 = (const float*)d_in[5];
    const float* W3 = (const float*)d_in[6];
    const float* b3 = (const float*)d_in[7];
    float* out = (float*)d_out;

    const int N = in_sizes[0] / 64;   // 100000
    const int E = in_sizes[1] / 2;    // 600000
    const int* src = ei;
    const int* dst = ei + E;

    // workspace carve
    char* p = (char*)d_ws;
    int*   deg   = (int*)p;   p += alignup((size_t)N * 4);
    float* dinv  = (float*)p; p += alignup((size_t)N * 4);
    int*   rowp  = (int*)p;   p += alignup((size_t)N * 4);
    int*   cnt   = (int*)p;   p += alignup((size_t)N * 4);
    int*   esrc  = (int*)p;   p += alignup((size_t)E * 4);
    float* enorm = (float*)p; p += alignup((size_t)E * 4);
    const int NB = (N + THREADS - 1) / THREADS;
    int*   bsums = (int*)p;   p += alignup((size_t)NB * 4);
    short* Wth   = (short*)p; p += alignup((size_t)256 * 256 * 2);
    short* Wtl   = (short*)p; p += alignup((size_t)256 * 256 * 2);
    float* bufA  = (float*)p; p += alignup((size_t)N * 256 * 4);

    const int EB = (E + THREADS - 1) / THREADS;
    const int GB = (N + 63) / 64;       // gemm blocks (64 rows each)
    const int AB = (N + 3) / 4;         // agg blocks (4 waves/block)

    hipMemsetAsync(deg, 0, (size_t)N * 4, stream);
    hipMemsetAsync(cnt, 0, (size_t)N * 4, stream);

    k_deg<<<EB, THREADS, 0, stream>>>(dst, deg, E);
    k_dinv<<<NB, THREADS, 0, stream>>>(deg, dinv, N);
    k_scan1<<<NB, THREADS, 0, stream>>>(deg, rowp, bsums, N);
    k_scan2<<<1, 512, 0, stream>>>(bsums, NB);
    k_scan3<<<NB, THREADS, 0, stream>>>(rowp, bsums, N);
    k_fill<<<EB, THREADS, 0, stream>>>(src, dst, dinv, rowp, cnt, esrc, enorm, E);

    // layer 1: x[N,64] @ W1
    k_wsplit<<<(256 * 64 + THREADS - 1) / THREADS, THREADS, 0, stream>>>(W1, Wth, Wtl, 64);
    k_mgemm<64><<<GB, THREADS, 0, stream>>>(x, Wth, Wtl, bufA, N);
    k_agg<<<AB, THREADS, 0, stream>>>(bufA, rowp, deg, esrc, enorm, b1, out, N);
    // layer 2
    k_wsplit<<<(256 * 256 + THREADS - 1) / THREADS, THREADS, 0, stream>>>(W2, Wth, Wtl, 256);
    k_mgemm<256><<<GB, THREADS, 0, stream>>>(out, Wth, Wtl, bufA, N);
    k_agg<<<AB, THREADS, 0, stream>>>(bufA, rowp, deg, esrc, enorm, b2, out, N);
    // layer 3
    k_wsplit<<<(256 * 256 + THREADS - 1) / THREADS, THREADS, 0, stream>>>(W3, Wth, Wtl, 256);
    k_mgemm<256><<<GB, THREADS, 0, stream>>>(out, Wth, Wtl, bufA, N);
    k_agg<<<AB, THREADS, 0, stream>>>(bufA, rowp, deg, esrc, enorm, b3, out, N);
}

// Round 5
// 650.818 us; speedup vs baseline: 24.6683x; 1.5523x over previous
//
#include <hip/hip_runtime.h>
#include <hip/hip_bf16.h>
#include <math.h>

// ---------------------------------------------------------------------------
// 3-layer GCN (PyG GCNConv, no self loops).
// R5: R4's split-bf16 MFMA GEMM was latency-bound (MfmaUtil 6.8%, VGPR=52,
// B-frag loads from L2 serialized against MFMA). Fix:
//  - B pre-packed fragment-major (k_wsplit2): frag(t,ct,plane)[lane][8]
//    -> staging loads are contiguous 1KB/wave, LDS reads lane-linear.
//  - global_load_lds double-buffered LDS staging, 2-phase pipeline
//    (STAGE(t+1) issued before compute(t); __syncthreads() drains).
//  - BM=128/block (4 waves x 32 rows): each B pair feeds 6 MFMAs.
//  - A raw prefetch (t+1) in named regs, split f32->bf16 hi/lo at use.
// Numerics identical to R4 (absmax 1.95e-3 passed): x*w ~ hi*wh+hi*wl+lo*wh.
// k_agg: 2-way unrolled edge loop (independent acc) to cut dep-chain.
// ---------------------------------------------------------------------------

#define THREADS 256

typedef __attribute__((ext_vector_type(8))) short short8;
typedef __attribute__((ext_vector_type(4))) float f32x4;

__global__ void k_deg(const int* __restrict__ dst, int* __restrict__ deg, int E) {
    int e = blockIdx.x * THREADS + threadIdx.x;
    if (e < E) atomicAdd(&deg[dst[e]], 1);
}

__global__ void k_dinv(const int* __restrict__ deg, float* __restrict__ dinv, int N) {
    int i = blockIdx.x * THREADS + threadIdx.x;
    if (i < N) {
        int d = deg[i];
        dinv[i] = (d > 0) ? rsqrtf((float)d) : 0.0f;
    }
}

__global__ void k_scan1(const int* __restrict__ deg, int* __restrict__ rowp,
                        int* __restrict__ bsums, int N) {
    __shared__ int s[THREADS];
    int idx = blockIdx.x * THREADS + threadIdx.x;
    int v = (idx < N) ? deg[idx] : 0;
    s[threadIdx.x] = v;
    __syncthreads();
    for (int off = 1; off < THREADS; off <<= 1) {
        int t = (threadIdx.x >= off) ? s[threadIdx.x - off] : 0;
        __syncthreads();
        s[threadIdx.x] += t;
        __syncthreads();
    }
    if (idx < N) rowp[idx] = s[threadIdx.x] - v;   // exclusive
    if (threadIdx.x == THREADS - 1) bsums[blockIdx.x] = s[threadIdx.x];
}

__global__ void k_scan2(int* __restrict__ bsums, int NB) {
    __shared__ int s[512];
    int v = (threadIdx.x < (unsigned)NB) ? bsums[threadIdx.x] : 0;
    s[threadIdx.x] = v;
    __syncthreads();
    for (int off = 1; off < 512; off <<= 1) {
        int t = (threadIdx.x >= (unsigned)off) ? s[threadIdx.x - off] : 0;
        __syncthreads();
        s[threadIdx.x] += t;
        __syncthreads();
    }
    if (threadIdx.x < (unsigned)NB) bsums[threadIdx.x] = s[threadIdx.x] - v;  // exclusive
}

__global__ void k_scan3(int* __restrict__ rowp, const int* __restrict__ bsums, int N) {
    int idx = blockIdx.x * THREADS + threadIdx.x;
    if (idx < N) rowp[idx] += bsums[blockIdx.x];
}

__global__ void k_fill(const int* __restrict__ src, const int* __restrict__ dst,
                       const float* __restrict__ dinv, const int* __restrict__ rowp,
                       int* __restrict__ cnt, int* __restrict__ esrc,
                       float* __restrict__ enorm, int E) {
    int e = blockIdx.x * THREADS + threadIdx.x;
    if (e >= E) return;
    int s = src[e], d = dst[e];
    int pos = rowp[d] + atomicAdd(&cnt[d], 1);
    esrc[pos]  = s;
    enorm[pos] = dinv[s] * dinv[d];
}

// ---- bf16 split helpers (round-to-nearest-even) ----
__device__ __forceinline__ unsigned bf16rn(float x) {
    unsigned u = __float_as_uint(x);
    return (u + 0x7FFFu + ((u >> 16) & 1u)) >> 16;
}
__device__ __forceinline__ void split1(float x, short8& h, short8& l, int e) {
    unsigned hb = bf16rn(x);
    float hf = __uint_as_float(hb << 16);
    h[e] = (short)hb;
    l[e] = (short)bf16rn(x - hf);
}
__device__ __forceinline__ void split4(float4 v, short8& h, short8& l, int e0) {
    split1(v.x, h, l, e0 + 0);
    split1(v.y, h, l, e0 + 1);
    split1(v.z, h, l, e0 + 2);
    split1(v.w, h, l, e0 + 3);
}

// W[K,256] -> Bpack fragment-major:
// frag index fr = (t*16+ct)*2+plane ; element = Bpack[fr*512 + lane*8 + e]
// where lane = kb*16 + r ; value = split(W[t*32+kb*8+e][ct*16+r])
__global__ void k_wsplit2(const float* __restrict__ W, short* __restrict__ Bp, int K) {
    int idx = blockIdx.x * THREADS + threadIdx.x;
    if (idx >= K * 256) return;
    int k = idx >> 8;
    int c = idx & 255;
    int t = k >> 5, kb = (k >> 3) & 3, e = k & 7;
    int ct = c >> 4, r = c & 15;
    float w = W[(size_t)k * 256 + c];
    unsigned hb = bf16rn(w);
    float hf = __uint_as_float(hb << 16);
    size_t base = ((size_t)(t * 16 + ct) * 2) * 512 + (kb * 16 + r) * 8 + e;
    Bp[base]       = (short)hb;
    Bp[base + 512] = (short)bf16rn(w - hf);
}

__device__ __forceinline__ void load_lds16(const void* g, void* l) {
    __builtin_amdgcn_global_load_lds(
        (const __attribute__((address_space(1))) void*)g,
        (__attribute__((address_space(3))) void*)l, 16, 0, 0);
}

// C[N,256] = act[N,K] @ W[K,256] via split-bf16 MFMA.
// Block = 256 threads = 4 waves. BM=128 (wave owns 32 rows: groups g0,g1 of
// 16), BN=256 (16 col-tiles), BK=32 per step. B staged in LDS (dbuf).
template <int K>
__global__ __launch_bounds__(256) void k_mgemm(const float* __restrict__ act,
                                               const short* __restrict__ Bpack,
                                               float* __restrict__ C, int N) {
    constexpr int NT = K / 32;
    __shared__ short Blds[2 * 16384];   // 2 x 32KB

    const int tid  = threadIdx.x;
    const int lane = tid & 63;
    const int wv   = tid >> 6;
    const int r    = lane & 15;
    const int kb   = lane >> 4;
    const int row0 = blockIdx.x * 128 + wv * 32;

    int ra = row0 + r;       if (ra >= N) ra = N - 1;
    int rb = row0 + 16 + r;  if (rb >= N) rb = N - 1;
    const float* apa = act + (size_t)ra * K + kb * 8;
    const float* apb = act + (size_t)rb * K + kb * 8;

    f32x4 acc0[16], acc1[16];
#pragma unroll
    for (int ct = 0; ct < 16; ++ct) { acc0[ct] = (f32x4)0.0f; acc1[ct] = (f32x4)0.0f; }

    // prologue: stage t=0, load raw A(0)
#pragma unroll
    for (int it = 0; it < 8; ++it)
        load_lds16(Bpack + it * 2048 + wv * 512 + lane * 8,
                   Blds + it * 2048 + wv * 512);
    float4 c00 = *(const float4*)(apa);
    float4 c01 = *(const float4*)(apa + 4);
    float4 c10 = *(const float4*)(apb);
    float4 c11 = *(const float4*)(apb + 4);
    __syncthreads();

    int cur = 0;
#pragma unroll 1
    for (int t = 0; t < NT; ++t) {
        float4 n00, n01, n10, n11;
        if (t + 1 < NT) {
            // stage B(t+1) into other buffer; prefetch raw A(t+1)
            const short* src = Bpack + (size_t)(t + 1) * 16384;
            short* dst = Blds + (cur ^ 1) * 16384;
#pragma unroll
            for (int it = 0; it < 8; ++it)
                load_lds16(src + it * 2048 + wv * 512 + lane * 8,
                           dst + it * 2048 + wv * 512);
            n00 = *(const float4*)(apa + (t + 1) * 32);
            n01 = *(const float4*)(apa + (t + 1) * 32 + 4);
            n10 = *(const float4*)(apb + (t + 1) * 32);
            n11 = *(const float4*)(apb + (t + 1) * 32 + 4);
        }

        // split current raw A into bf16 hi/lo fragments
        short8 ah0, al0, ah1, al1;
        split4(c00, ah0, al0, 0); split4(c01, ah0, al0, 4);
        split4(c10, ah1, al1, 0); split4(c11, ah1, al1, 4);

        const short* bb = Blds + cur * 16384;
#pragma unroll
        for (int ct = 0; ct < 16; ++ct) {
            short8 bh = *(const short8*)(bb + (ct * 2 + 0) * 512 + lane * 8);
            short8 bl = *(const short8*)(bb + (ct * 2 + 1) * 512 + lane * 8);
            acc0[ct] = __builtin_amdgcn_mfma_f32_16x16x32_bf16(ah0, bh, acc0[ct], 0, 0, 0);
            acc0[ct] = __builtin_amdgcn_mfma_f32_16x16x32_bf16(ah0, bl, acc0[ct], 0, 0, 0);
            acc0[ct] = __builtin_amdgcn_mfma_f32_16x16x32_bf16(al0, bh, acc0[ct], 0, 0, 0);
            acc1[ct] = __builtin_amdgcn_mfma_f32_16x16x32_bf16(ah1, bh, acc1[ct], 0, 0, 0);
            acc1[ct] = __builtin_amdgcn_mfma_f32_16x16x32_bf16(ah1, bl, acc1[ct], 0, 0, 0);
            acc1[ct] = __builtin_amdgcn_mfma_f32_16x16x32_bf16(al1, bh, acc1[ct], 0, 0, 0);
        }
        __syncthreads();   // drains stage(t+1) vmcnt; waves done reading cur

        if (t + 1 < NT) { c00 = n00; c01 = n01; c10 = n10; c11 = n11; }
        cur ^= 1;
    }

    // C/D layout: row = 4*(lane>>4)+reg, col = lane&15 (within tile)
#pragma unroll
    for (int jr = 0; jr < 4; ++jr) {
        int g0 = row0 + kb * 4 + jr;
        if (g0 < N) {
            float* cp = C + (size_t)g0 * 256 + r;
#pragma unroll
            for (int ct = 0; ct < 16; ++ct) cp[ct * 16] = acc0[ct][jr];
        }
        int g1 = row0 + 16 + kb * 4 + jr;
        if (g1 < N) {
            float* cp = C + (size_t)g1 * 256 + r;
#pragma unroll
            for (int ct = 0; ct < 16; ++ct) cp[ct * 16] = acc1[ct][jr];
        }
    }
}

__device__ __forceinline__ float elu1(float x) {
    return x > 0.0f ? x : expm1f(x);
}

// one wave per node; lane handles 4 channels. 2-way unrolled edge loop.
__global__ __launch_bounds__(256) void k_agg(const float* __restrict__ h,
                                             const int* __restrict__ rowp,
                                             const int* __restrict__ deg,
                                             const int* __restrict__ esrc,
                                             const float* __restrict__ enorm,
                                             const float* __restrict__ bias,
                                             float* __restrict__ out, int N) {
    int wave = threadIdx.x >> 6;
    int lane = threadIdx.x & 63;
    int node = blockIdx.x * 4 + wave;
    if (node >= N) return;

    int start = rowp[node];
    int cnt   = deg[node];

    float4 acc = make_float4(0.f, 0.f, 0.f, 0.f);
    float4 acc2 = make_float4(0.f, 0.f, 0.f, 0.f);
    int e = 0;
    for (; e + 2 <= cnt; e += 2) {
        int   s0 = esrc[start + e];
        int   s1 = esrc[start + e + 1];
        float n0 = enorm[start + e];
        float n1 = enorm[start + e + 1];
        float4 h0 = *(const float4*)&h[(size_t)s0 * 256 + lane * 4];
        float4 h1 = *(const float4*)&h[(size_t)s1 * 256 + lane * 4];
        acc.x += n0 * h0.x;  acc.y += n0 * h0.y;
        acc.z += n0 * h0.z;  acc.w += n0 * h0.w;
        acc2.x += n1 * h1.x; acc2.y += n1 * h1.y;
        acc2.z += n1 * h1.z; acc2.w += n1 * h1.w;
    }
    if (e < cnt) {
        int   s0 = esrc[start + e];
        float n0 = enorm[start + e];
        float4 h0 = *(const float4*)&h[(size_t)s0 * 256 + lane * 4];
        acc.x += n0 * h0.x; acc.y += n0 * h0.y;
        acc.z += n0 * h0.z; acc.w += n0 * h0.w;
    }
    acc.x += acc2.x; acc.y += acc2.y; acc.z += acc2.z; acc.w += acc2.w;

    float4 b4 = *(const float4*)&bias[lane * 4];
    float4 o;
    o.x = elu1(acc.x + b4.x);
    o.y = elu1(acc.y + b4.y);
    o.z = elu1(acc.z + b4.z);
    o.w = elu1(acc.w + b4.w);
    *(float4*)&out[(size_t)node * 256 + lane * 4] = o;
}

static inline size_t alignup(size_t x) { return (x + 255) & ~(size_t)255; }

extern "C" void kernel_launch(void* const* d_in, const int* in_sizes, int n_in,
                              void* d_out, int out_size, void* d_ws, size_t ws_size,
                              hipStream_t stream) {
    const float* x  = (const float*)d_in[0];
    const int*   ei = (const int*)d_in[1];
    const float* W1 = (const float*)d_in[2];
    const float* b1 = (const float*)d_in[3];
    const float* W2 = (const float*)d_in[4];
    const float* b2 = (const float*)d_in[5];
    const float* W3 = (const float*)d_in[6];
    const float* b3 = (const float*)d_in[7];
    float* out = (float*)d_out;

    const int N = in_sizes[0] / 64;   // 100000
    const int E = in_sizes[1] / 2;    // 600000
    const int* src = ei;
    const int* dst = ei + E;

    // workspace carve
    char* p = (char*)d_ws;
    int*   deg   = (int*)p;   p += alignup((size_t)N * 4);
    float* dinv  = (float*)p; p += alignup((size_t)N * 4);
    int*   rowp  = (int*)p;   p += alignup((size_t)N * 4);
    int*   cnt   = (int*)p;   p += alignup((size_t)N * 4);
    int*   esrc  = (int*)p;   p += alignup((size_t)E * 4);
    float* enorm = (float*)p; p += alignup((size_t)E * 4);
    const int NB = (N + THREADS - 1) / THREADS;
    int*   bsums = (int*)p;   p += alignup((size_t)NB * 4);
    short* Bpack = (short*)p; p += alignup((size_t)256 * 256 * 2 * 2); // 256KB max
    float* bufA  = (float*)p; p += alignup((size_t)N * 256 * 4);

    const int EB = (E + THREADS - 1) / THREADS;
    const int GB = (N + 127) / 128;     // gemm blocks (128 rows each)
    const int AB = (N + 3) / 4;         // agg blocks (4 waves/block)

    hipMemsetAsync(deg, 0, (size_t)N * 4, stream);
    hipMemsetAsync(cnt, 0, (size_t)N * 4, stream);

    k_deg<<<EB, THREADS, 0, stream>>>(dst, deg, E);
    k_dinv<<<NB, THREADS, 0, stream>>>(deg, dinv, N);
    k_scan1<<<NB, THREADS, 0, stream>>>(deg, rowp, bsums, N);
    k_scan2<<<1, 512, 0, stream>>>(bsums, NB);
    k_scan3<<<NB, THREADS, 0, stream>>>(rowp, bsums, N);
    k_fill<<<EB, THREADS, 0, stream>>>(src, dst, dinv, rowp, cnt, esrc, enorm, E);

    // layer 1: x[N,64] @ W1
    k_wsplit2<<<(64 * 256 + THREADS - 1) / THREADS, THREADS, 0, stream>>>(W1, Bpack, 64);
    k_mgemm<64><<<GB, THREADS, 0, stream>>>(x, Bpack, bufA, N);
    k_agg<<<AB, THREADS, 0, stream>>>(bufA, rowp, deg, esrc, enorm, b1, out, N);
    // layer 2
    k_wsplit2<<<(256 * 256 + THREADS - 1) / THREADS, THREADS, 0, stream>>>(W2, Bpack, 256);
    k_mgemm<256><<<GB, THREADS, 0, stream>>>(out, Bpack, bufA, N);
    k_agg<<<AB, THREADS, 0, stream>>>(bufA, rowp, deg, esrc, enorm, b2, out, N);
    // layer 3
    k_wsplit2<<<(256 * 256 + THREADS - 1) / THREADS, THREADS, 0, stream>>>(W3, Bpack, 256);
    k_mgemm<256><<<GB, THREADS, 0, stream>>>(out, Bpack, bufA, N);
    k_agg<<<AB, THREADS, 0, stream>>>(bufA, rowp, deg, esrc, enorm, b3, out, N);
}